// Round 1
// baseline (244.320 us; speedup 1.0000x reference)
//
#include <hip/hip_runtime.h>
#include <hip/hip_bf16.h>
#include <cstdint>
#include <cstddef>

typedef __bf16 bf16_t;
typedef __attribute__((ext_vector_type(8))) __bf16 bf16x8;
typedef __attribute__((ext_vector_type(4))) float f32x4;

#define ATT_EPS 1e-4f

__device__ __forceinline__ f32x4 mfma_bf16(bf16x8 a, bf16x8 b, f32x4 c) {
  return __builtin_amdgcn_mfma_f32_16x16x32_bf16(a, b, c, 0, 0, 0);
}

#define GLDS16(g, l)                                                          \
  __builtin_amdgcn_global_load_lds(                                           \
      (const __attribute__((address_space(1))) void*)(g),                     \
      (__attribute__((address_space(3))) void*)(l), 16, 0, 0)

// ---------------------------------------------------------------- convert X
__global__ __launch_bounds__(256) void cvt_x_kernel(
    const float* __restrict__ X, bf16_t* __restrict__ Xb, int n8) {
  int i = blockIdx.x * 256 + threadIdx.x;
  if (i >= n8) return;
  f32x4 a = ((const f32x4*)X)[i * 2 + 0];
  f32x4 b = ((const f32x4*)X)[i * 2 + 1];
  bf16x8 o;
  o[0] = (__bf16)a[0]; o[1] = (__bf16)a[1]; o[2] = (__bf16)a[2]; o[3] = (__bf16)a[3];
  o[4] = (__bf16)b[0]; o[5] = (__bf16)b[1]; o[6] = (__bf16)b[2]; o[7] = (__bf16)b[3];
  ((bf16x8*)Xb)[i] = o;
}

// --------------------------------------- transpose + convert: W[R][C] -> Wt[C][R]
__global__ __launch_bounds__(256) void tcvt_kernel(
    const float* __restrict__ W, bf16_t* __restrict__ Wt, int R, int C) {
  __shared__ float T[64][65];
  int tx = threadIdx.x & 63, ty = threadIdx.x >> 6;
  int c0 = blockIdx.x * 64, r0 = blockIdx.y * 64;
#pragma unroll
  for (int i = 0; i < 16; ++i) {
    int rr = ty * 16 + i;
    T[rr][tx] = W[(size_t)(r0 + rr) * C + c0 + tx];
  }
  __syncthreads();
#pragma unroll
  for (int i = 0; i < 16; ++i) {
    int cc = ty * 16 + i;
    Wt[(size_t)(c0 + cc) * R + r0 + tx] = (bf16_t)T[tx][cc];
  }
}

// ------------------------------------------------------------------- GEMM
// C[M][N] = A[M][K] * Bt[N][K]^T + bias, A/Bt bf16, acc f32.
// 128x128 tile, BK=64, 4 waves (2x2 of 64x64), 16x16x32 MFMA.
template <int OUTF32>
__global__ __launch_bounds__(256, 2) void gemm_kernel(
    const bf16_t* __restrict__ A, const bf16_t* __restrict__ Bt,
    const float* __restrict__ bias, void* __restrict__ Cout,
    int M, int N, int K) {
  __shared__ bf16_t As[2][128 * 64];
  __shared__ bf16_t Bs[2][128 * 64];
  int tid = threadIdx.x, lane = tid & 63, wv = tid >> 6;
  int l15 = lane & 15, lhi = lane >> 4;
  int NT = N >> 7;
  int nwg = gridDim.x;
  int qq = nwg >> 3;  // nwg % 8 == 0 for all our launches
  int swz = (blockIdx.x & 7) * qq + (blockIdx.x >> 3);
  int tm = swz / NT, tn = swz % NT;
  int m0 = tm << 7, n0 = tn << 7;
  int wm = (wv >> 1) << 6, wn = (wv & 1) << 6;
  int KT = K >> 6;

  auto stage = [&](int buf, int kt) {
    int k0 = kt << 6;
#pragma unroll
    for (int s = 0; s < 4; ++s) {
      int t = s * 256 + tid;
      int row = t >> 3, u = t & 7;
      int cc = (u ^ (row & 7)) << 3;
      GLDS16(A + (size_t)(m0 + row) * K + k0 + cc, &As[buf][t * 8]);
    }
#pragma unroll
    for (int s = 0; s < 4; ++s) {
      int t = s * 256 + tid;
      int row = t >> 3, u = t & 7;
      int cc = (u ^ (row & 7)) << 3;
      GLDS16(Bt + (size_t)(n0 + row) * K + k0 + cc, &Bs[buf][t * 8]);
    }
  };

  f32x4 zero = {0.f, 0.f, 0.f, 0.f};
  f32x4 acc[4][4];
#pragma unroll
  for (int ms = 0; ms < 4; ++ms)
#pragma unroll
    for (int ns = 0; ns < 4; ++ns) acc[ms][ns] = zero;

  stage(0, 0);
  __syncthreads();
  int cur = 0;
  for (int kt = 0; kt < KT; ++kt) {
    if (kt + 1 < KT) stage(cur ^ 1, kt + 1);
#pragma unroll
    for (int ks = 0; ks < 2; ++ks) {
      bf16x8 af[4], bfr[4];
#pragma unroll
      for (int ms = 0; ms < 4; ++ms) {
        int row = wm + ms * 16 + l15;
        af[ms] = *(const bf16x8*)&As[cur][row * 64 + (((ks * 4 + lhi) ^ (row & 7)) << 3)];
      }
#pragma unroll
      for (int ns = 0; ns < 4; ++ns) {
        int col = wn + ns * 16 + l15;
        bfr[ns] = *(const bf16x8*)&Bs[cur][col * 64 + (((ks * 4 + lhi) ^ (col & 7)) << 3)];
      }
#pragma unroll
      for (int ms = 0; ms < 4; ++ms)
#pragma unroll
        for (int ns = 0; ns < 4; ++ns)
          acc[ms][ns] = mfma_bf16(af[ms], bfr[ns], acc[ms][ns]);
    }
    __syncthreads();
    cur ^= 1;
  }

#pragma unroll
  for (int ns = 0; ns < 4; ++ns) {
    int col = n0 + wn + ns * 16 + l15;
    float bv = bias[col];
#pragma unroll
    for (int ms = 0; ms < 4; ++ms) {
      int rowb = m0 + wm + ms * 16 + lhi * 4;
#pragma unroll
      for (int r = 0; r < 4; ++r) {
        float v = acc[ms][ns][r] + bv;
        if (OUTF32)
          ((float*)Cout)[(size_t)(rowb + r) * N + col] = v;
        else
          ((bf16_t*)Cout)[(size_t)(rowb + r) * N + col] = (bf16_t)v;
      }
    }
  }
}

// --------------------------------------------------- row sum-of-squares of Q,K
// P[4096][4096]; Q cols h*256+0..63, K cols h*256+64..127.
__global__ __launch_bounds__(256) void norms_kernel(
    const bf16_t* __restrict__ P, float* __restrict__ Q2, float* __restrict__ K2) {
  int tid = threadIdx.x, lane = tid & 63, wv = tid >> 6;
  int wg = blockIdx.x * 4 + wv;  // 0..8191
  int h = wg >> 9, rb = wg & 511;
  int r = rb * 8 + (lane >> 3), ch = lane & 7;
  const bf16_t* base = P + (size_t)r * 4096 + h * 256 + ch * 8;
  bf16x8 qv = *(const bf16x8*)base;
  bf16x8 kv = *(const bf16x8*)(base + 64);
  float sq = 0.f, sk = 0.f;
#pragma unroll
  for (int j = 0; j < 8; ++j) {
    float a = (float)qv[j];
    sq += a * a;
    float c = (float)kv[j];
    sk += c * c;
  }
#pragma unroll
  for (int m = 1; m <= 4; m <<= 1) {
    sq += __shfl_xor(sq, m);
    sk += __shfl_xor(sk, m);
  }
  if (ch == 0) {
    Q2[h * 4096 + r] = sq;
    K2[h * 4096 + r] = sk;
  }
}

// ------------------------------------------------------- fused Shepard attention
// Per block: one (h, b, 128-row q-tile). 4 waves x 32 q-rows.
// numer[q][e] += w @ V over s-tiles of 128; denom[q] += sum_s w.
__global__ __launch_bounds__(256, 2) void attn_kernel(
    const bf16_t* __restrict__ P, const float* __restrict__ Q2,
    const float* __restrict__ K2, bf16_t* __restrict__ H) {
  __shared__ bf16_t Ks[128 * 64];      // swizzled chunks, 16KB
  __shared__ bf16_t Vt[64 * 136];      // V^T, padded rows
  __shared__ bf16_t Wb[4][32 * 136];   // per-wave w buffer

  int tid = threadIdx.x, lane = tid & 63, wv = tid >> 6;
  int l15 = lane & 15, lhi = lane >> 4;
  int swz = (blockIdx.x & 7) * 64 + (blockIdx.x >> 3);  // 512 blocks
  int hb = swz >> 4, qt = swz & 15;
  int h = hb >> 1, b = hb & 1;
  int rowbase = b * 2048;
  const bf16_t* Pq = P + (size_t)rowbase * 4096 + h * 256;
  const bf16_t* Pk = Pq + 64;
  const bf16_t* Pv = Pq + 128;
  const bf16_t* Pg = Pq + 192;
  int q0 = qt * 128 + wv * 32;

  // Q fragments (held in registers for the whole kernel)
  bf16x8 qf[2][2];
#pragma unroll
  for (int qs = 0; qs < 2; ++qs)
#pragma unroll
    for (int ks = 0; ks < 2; ++ks) {
      int row = q0 + qs * 16 + l15;
      qf[qs][ks] = *(const bf16x8*)(Pq + (size_t)row * 4096 + ks * 32 + lhi * 8);
    }
  float q2d[2][4];
#pragma unroll
  for (int qs = 0; qs < 2; ++qs)
#pragma unroll
    for (int r = 0; r < 4; ++r)
      q2d[qs][r] = Q2[h * 4096 + rowbase + q0 + qs * 16 + lhi * 4 + r];

  f32x4 zero = {0.f, 0.f, 0.f, 0.f};
  f32x4 nacc[2][4];
  float denom[2][4];
#pragma unroll
  for (int qs = 0; qs < 2; ++qs) {
#pragma unroll
    for (int es = 0; es < 4; ++es) nacc[qs][es] = zero;
#pragma unroll
    for (int r = 0; r < 4; ++r) denom[qs][r] = 0.f;
  }

  int sv = wv * 32 + (lane & 31);
  int e0base = (lane >> 5) * 8;
  bf16_t* wbuf = &Wb[wv][0];

  for (int st = 0; st < 16; ++st) {
    int s0 = st * 128;
    __syncthreads();  // previous compute done: Ks/Vt reusable
    // stage K tile (global_load_lds, source-swizzled so reads are conflict-free)
#pragma unroll
    for (int s4 = 0; s4 < 4; ++s4) {
      int t = s4 * 256 + tid;
      int row = t >> 3, u = t & 7;
      int cc = (u ^ (row & 7)) << 3;
      GLDS16(Pk + (size_t)(s0 + row) * 4096 + cc, &Ks[t * 8]);
    }
    // stage V^T (reg-staged transpose)
    bf16x8 vr[4];
#pragma unroll
    for (int p = 0; p < 4; ++p)
      vr[p] = *(const bf16x8*)(Pv + (size_t)(s0 + sv) * 4096 + e0base + p * 16);
#pragma unroll
    for (int p = 0; p < 4; ++p) {
      int e0 = e0base + p * 16;
#pragma unroll
      for (int j = 0; j < 8; ++j) Vt[(e0 + j) * 136 + sv] = vr[p][j];
    }
    __syncthreads();  // Ks (vmcnt drained by barrier) + Vt visible

    // QK^T -> w -> Wb (per-wave private), accumulate denom
#pragma unroll
    for (int ss = 0; ss < 8; ++ss) {
      int srow = ss * 16 + l15;
      bf16x8 kf0 = *(const bf16x8*)&Ks[srow * 64 + ((lhi ^ (srow & 7)) << 3)];
      bf16x8 kf1 = *(const bf16x8*)&Ks[srow * 64 + (((4 + lhi) ^ (srow & 7)) << 3)];
      float k2s = K2[h * 4096 + rowbase + s0 + srow];
#pragma unroll
      for (int qs = 0; qs < 2; ++qs) {
        f32x4 S = mfma_bf16(qf[qs][0], kf0, zero);
        S = mfma_bf16(qf[qs][1], kf1, S);
#pragma unroll
        for (int r = 0; r < 4; ++r) {
          float d2 = q2d[qs][r] + k2s - 2.0f * S[r];
          float d = sqrtf(fmaxf(d2, 0.f));
          float w = 1.0f / (ATT_EPS + d);
          w = w * w;
          denom[qs][r] += w;
          wbuf[(qs * 16 + lhi * 4 + r) * 136 + ss * 16 + l15] = (bf16_t)w;
        }
      }
    }
    // PV: numer[q][e] += w[q][s] * V[s][e]
#pragma unroll
    for (int sk = 0; sk < 4; ++sk) {
      bf16x8 wf[2], vf[4];
#pragma unroll
      for (int qs = 0; qs < 2; ++qs)
        wf[qs] = *(const bf16x8*)&wbuf[(qs * 16 + l15) * 136 + sk * 32 + lhi * 8];
#pragma unroll
      for (int es = 0; es < 4; ++es)
        vf[es] = *(const bf16x8*)&Vt[(es * 16 + l15) * 136 + sk * 32 + lhi * 8];
#pragma unroll
      for (int qs = 0; qs < 2; ++qs)
#pragma unroll
        for (int es = 0; es < 4; ++es)
          nacc[qs][es] = mfma_bf16(wf[qs], vf[es], nacc[qs][es]);
    }
  }

  // reduce denom across the 16 s-columns (lanes l15)
#pragma unroll
  for (int m = 1; m <= 8; m <<= 1)
#pragma unroll
    for (int qs = 0; qs < 2; ++qs)
#pragma unroll
      for (int r = 0; r < 4; ++r) denom[qs][r] += __shfl_xor(denom[qs][r], m);

  // epilogue: A = numer/(eps+denom); H = G*A
#pragma unroll
  for (int qs = 0; qs < 2; ++qs)
#pragma unroll
    for (int r = 0; r < 4; ++r) {
      int tq = q0 + qs * 16 + lhi * 4 + r;  // t index within batch
      float inv = 1.0f / (ATT_EPS + denom[qs][r]);
#pragma unroll
      for (int es = 0; es < 4; ++es) {
        int ec = es * 16 + l15;
        float g = (float)Pg[(size_t)tq * 4096 + ec];
        float hv = g * nacc[qs][es][r] * inv;
        H[(size_t)(rowbase + tq) * 1024 + h * 64 + ec] = (bf16_t)hv;
      }
    }
}

// ------------------------------------------------------------------ launcher
extern "C" void kernel_launch(void* const* d_in, const int* in_sizes, int n_in,
                              void* d_out, int out_size, void* d_ws, size_t ws_size,
                              hipStream_t stream) {
  const float* X     = (const float*)d_in[0];
  const float* W_in  = (const float*)d_in[1];
  const float* b_in  = (const float*)d_in[2];
  const float* W_out = (const float*)d_in[3];
  const float* b_out = (const float*)d_in[4];

  char* ws = (char*)d_ws;
  bf16_t* Xb  = (bf16_t*)(ws);                        // 8 MB
  bf16_t* WbT = (bf16_t*)(ws + ((size_t)8  << 20));   // 8 MB
  bf16_t* WoT = (bf16_t*)(ws + ((size_t)16 << 20));   // 2 MB
  bf16_t* Pb  = (bf16_t*)(ws + ((size_t)18 << 20));   // 32 MB
  bf16_t* Hb  = (bf16_t*)(ws + ((size_t)50 << 20));   // 8 MB
  float*  Q2  = (float*) (ws + ((size_t)58 << 20));   // 256 KB
  float*  K2  = (float*) (ws + ((size_t)59 << 20));   // 256 KB

  cvt_x_kernel<<<2048, 256, 0, stream>>>(X, Xb, 4096 * 1024 / 8);
  tcvt_kernel<<<dim3(64, 16), 256, 0, stream>>>(W_in, WbT, 1024, 4096);
  tcvt_kernel<<<dim3(16, 16), 256, 0, stream>>>(W_out, WoT, 1024, 1024);
  gemm_kernel<0><<<1024, 256, 0, stream>>>(Xb, WbT, b_in, Pb, 4096, 4096, 1024);
  norms_kernel<<<2048, 256, 0, stream>>>(Pb, Q2, K2);
  attn_kernel<<<512, 256, 0, stream>>>(Pb, Q2, K2, Hb);
  gemm_kernel<1><<<256, 256, 0, stream>>>(Hb, WoT, b_out, d_out, 4096, 1024, 1024);
}

// Round 2
// 143.312 us; speedup vs baseline: 1.7048x; 1.7048x over previous
//
#include <hip/hip_runtime.h>
#include <hip/hip_bf16.h>
#include <cstdint>
#include <cstddef>

typedef __bf16 bf16_t;
typedef __attribute__((ext_vector_type(8))) __bf16 bf16x8;
typedef __attribute__((ext_vector_type(4))) __bf16 bf16x4;
typedef __attribute__((ext_vector_type(4))) float f32x4;
typedef __attribute__((ext_vector_type(4))) unsigned int u32x4;

#define ATT_EPS 1e-4f

__device__ __forceinline__ f32x4 mfma_bf16(bf16x8 a, bf16x8 b, f32x4 c) {
  return __builtin_amdgcn_mfma_f32_16x16x32_bf16(a, b, c, 0, 0, 0);
}

#define GLDS16(g, l)                                                          \
  __builtin_amdgcn_global_load_lds(                                           \
      (const __attribute__((address_space(1))) void*)(g),                     \
      (__attribute__((address_space(3))) void*)(l), 16, 0, 0)

// ---------------------------------------------------------------- convert X
__global__ __launch_bounds__(256) void cvt_x_kernel(
    const float* __restrict__ X, bf16_t* __restrict__ Xb, int n8) {
  int i = blockIdx.x * 256 + threadIdx.x;
  if (i >= n8) return;
  f32x4 a = ((const f32x4*)X)[i * 2 + 0];
  f32x4 b = ((const f32x4*)X)[i * 2 + 1];
  bf16x8 o;
  o[0] = (__bf16)a[0]; o[1] = (__bf16)a[1]; o[2] = (__bf16)a[2]; o[3] = (__bf16)a[3];
  o[4] = (__bf16)b[0]; o[5] = (__bf16)b[1]; o[6] = (__bf16)b[2]; o[7] = (__bf16)b[3];
  ((bf16x8*)Xb)[i] = o;
}

// --------------------------------------- transpose + convert: W[R][C] -> Wt[C][R]
__global__ __launch_bounds__(256) void tcvt_kernel(
    const float* __restrict__ W, bf16_t* __restrict__ Wt, int R, int C) {
  __shared__ float T[64][65];
  int tx = threadIdx.x & 63, ty = threadIdx.x >> 6;
  int c0 = blockIdx.x * 64, r0 = blockIdx.y * 64;
#pragma unroll
  for (int i = 0; i < 16; ++i) {
    int rr = ty * 16 + i;
    T[rr][tx] = W[(size_t)(r0 + rr) * C + c0 + tx];
  }
  __syncthreads();
#pragma unroll
  for (int i = 0; i < 16; ++i) {
    int cc = ty * 16 + i;
    Wt[(size_t)(c0 + cc) * R + r0 + tx] = (bf16_t)T[tx][cc];
  }
}

// ---------------------------------- V transpose: P's V-cols -> VtG[h*64+e][4096]
__global__ __launch_bounds__(256) void vt_kernel(
    const bf16_t* __restrict__ P, bf16_t* __restrict__ VtG) {
  __shared__ float T[64][65];
  int h = blockIdx.x;
  int r0 = blockIdx.y * 64;
  int tx = threadIdx.x & 63, ty = threadIdx.x >> 6;
  const bf16_t* src = P + (size_t)r0 * 4096 + h * 256 + 128;
#pragma unroll
  for (int i = 0; i < 16; ++i) {
    int rr = ty * 16 + i;
    T[rr][tx] = (float)src[(size_t)rr * 4096 + tx];
  }
  __syncthreads();
#pragma unroll
  for (int i = 0; i < 16; ++i) {
    int cc = ty * 16 + i;
    VtG[(size_t)(h * 64 + cc) * 4096 + r0 + tx] = (bf16_t)T[tx][cc];
  }
}

// ------------------------------------------------------------------- GEMM
template <int OUTF32>
__global__ __launch_bounds__(256, 2) void gemm_kernel(
    const bf16_t* __restrict__ A, const bf16_t* __restrict__ Bt,
    const float* __restrict__ bias, void* __restrict__ Cout,
    int M, int N, int K) {
  __shared__ bf16_t As[2][128 * 64];
  __shared__ bf16_t Bs[2][128 * 64];
  int tid = threadIdx.x, lane = tid & 63, wv = tid >> 6;
  int l15 = lane & 15, lhi = lane >> 4;
  int NT = N >> 7;
  int nwg = gridDim.x;
  int qq = nwg >> 3;
  int swz = (blockIdx.x & 7) * qq + (blockIdx.x >> 3);
  int tm = swz / NT, tn = swz % NT;
  int m0 = tm << 7, n0 = tn << 7;
  int wm = (wv >> 1) << 6, wn = (wv & 1) << 6;
  int KT = K >> 6;

  auto stage = [&](int buf, int kt) {
    int k0 = kt << 6;
#pragma unroll
    for (int s = 0; s < 4; ++s) {
      int t = s * 256 + tid;
      int row = t >> 3, u = t & 7;
      int cc = (u ^ (row & 7)) << 3;
      GLDS16(A + (size_t)(m0 + row) * K + k0 + cc, &As[buf][t * 8]);
    }
#pragma unroll
    for (int s = 0; s < 4; ++s) {
      int t = s * 256 + tid;
      int row = t >> 3, u = t & 7;
      int cc = (u ^ (row & 7)) << 3;
      GLDS16(Bt + (size_t)(n0 + row) * K + k0 + cc, &Bs[buf][t * 8]);
    }
  };

  f32x4 zero = {0.f, 0.f, 0.f, 0.f};
  f32x4 acc[4][4];
#pragma unroll
  for (int ms = 0; ms < 4; ++ms)
#pragma unroll
    for (int ns = 0; ns < 4; ++ns) acc[ms][ns] = zero;

  stage(0, 0);
  __syncthreads();
  int cur = 0;
  for (int kt = 0; kt < KT; ++kt) {
    if (kt + 1 < KT) stage(cur ^ 1, kt + 1);
#pragma unroll
    for (int ks = 0; ks < 2; ++ks) {
      bf16x8 af[4], bfr[4];
#pragma unroll
      for (int ms = 0; ms < 4; ++ms) {
        int row = wm + ms * 16 + l15;
        af[ms] = *(const bf16x8*)&As[cur][row * 64 + (((ks * 4 + lhi) ^ (row & 7)) << 3)];
      }
#pragma unroll
      for (int ns = 0; ns < 4; ++ns) {
        int col = wn + ns * 16 + l15;
        bfr[ns] = *(const bf16x8*)&Bs[cur][col * 64 + (((ks * 4 + lhi) ^ (col & 7)) << 3)];
      }
#pragma unroll
      for (int ms = 0; ms < 4; ++ms)
#pragma unroll
        for (int ns = 0; ns < 4; ++ns)
          acc[ms][ns] = mfma_bf16(af[ms], bfr[ns], acc[ms][ns]);
    }
    __syncthreads();
    cur ^= 1;
  }

#pragma unroll
  for (int ns = 0; ns < 4; ++ns) {
    int col = n0 + wn + ns * 16 + l15;
    float bv = bias[col];
#pragma unroll
    for (int ms = 0; ms < 4; ++ms) {
      int rowb = m0 + wm + ms * 16 + lhi * 4;
#pragma unroll
      for (int r = 0; r < 4; ++r) {
        float v = acc[ms][ns][r] + bv;
        if (OUTF32)
          ((float*)Cout)[(size_t)(rowb + r) * N + col] = v;
        else
          ((bf16_t*)Cout)[(size_t)(rowb + r) * N + col] = (bf16_t)v;
      }
    }
  }
}

// --------------------------------------------------- row sum-of-squares of Q,K
__global__ __launch_bounds__(256) void norms_kernel(
    const bf16_t* __restrict__ P, float* __restrict__ Q2, float* __restrict__ K2) {
  int tid = threadIdx.x, lane = tid & 63, wv = tid >> 6;
  int wg = blockIdx.x * 4 + wv;
  int h = wg >> 9, rb = wg & 511;
  int r = rb * 8 + (lane >> 3), ch = lane & 7;
  const bf16_t* base = P + (size_t)r * 4096 + h * 256 + ch * 8;
  bf16x8 qv = *(const bf16x8*)base;
  bf16x8 kv = *(const bf16x8*)(base + 64);
  float sq = 0.f, sk = 0.f;
#pragma unroll
  for (int j = 0; j < 8; ++j) {
    float a = (float)qv[j];
    sq += a * a;
    float c = (float)kv[j];
    sk += c * c;
  }
#pragma unroll
  for (int m = 1; m <= 4; m <<= 1) {
    sq += __shfl_xor(sq, m);
    sk += __shfl_xor(sk, m);
  }
  if (ch == 0) {
    Q2[h * 4096 + r] = sq;
    K2[h * 4096 + r] = sk;
  }
}

// ------------------------------------------------------- fused Shepard attention
// Swapped QK^T: D[s][q] = K . (-2Q)^T with C-init = k2 vector; d2 = D + q2.
// w = 1/d2 (matches (eps+d)^-2 to ~2e-5 rel). Packed b64 w-writes; V^T staged
// from pre-transposed global VtG via global_load_lds.
__global__ __launch_bounds__(256, 2) void attn_kernel(
    const bf16_t* __restrict__ P, const bf16_t* __restrict__ VtG,
    const float* __restrict__ Q2, const float* __restrict__ K2,
    bf16_t* __restrict__ H) {
  __shared__ bf16_t Ks[128 * 64];      // K tile, swizzled chunks, 16KB
  __shared__ bf16_t Vts[64 * 128];     // V^T tile, swizzled chunks, 16KB
  __shared__ bf16_t Wb[4][32 * 136];   // per-wave w buffer, 34.8KB

  int tid = threadIdx.x, lane = tid & 63, wv = tid >> 6;
  int l15 = lane & 15, lhi = lane >> 4;
  int swz = (blockIdx.x & 7) * 64 + (blockIdx.x >> 3);
  int hb = swz >> 4, qt = swz & 15;
  int h = hb >> 1, b = hb & 1;
  int rowbase = b * 2048;
  const bf16_t* Pq = P + (size_t)rowbase * 4096 + h * 256;
  const bf16_t* Pk = Pq + 64;
  const bf16_t* Pg = Pq + 192;
  const bf16_t* Vg = VtG + (size_t)h * 64 * 4096 + rowbase;
  const float* Q2g = Q2 + h * 4096 + rowbase;
  const float* K2g = K2 + h * 4096 + rowbase;
  int q0 = qt * 128 + wv * 32;

  // Q fragments scaled by -2 (bf16 sign-flip + exponent+1; packed u32 trick)
  bf16x8 qm[2][2];
#pragma unroll
  for (int qs = 0; qs < 2; ++qs)
#pragma unroll
    for (int ks = 0; ks < 2; ++ks) {
      int row = q0 + qs * 16 + l15;
      bf16x8 q = *(const bf16x8*)(Pq + (size_t)row * 4096 + ks * 32 + lhi * 8);
      u32x4 u = *(u32x4*)&q;
      u = (u ^ 0x80008000u) + 0x00800080u;
      qm[qs][ks] = *(bf16x8*)&u;
    }
  float q2v[2];
#pragma unroll
  for (int qs = 0; qs < 2; ++qs) q2v[qs] = Q2g[q0 + qs * 16 + l15];

  f32x4 nacc[2][4];
  float dacc[2] = {0.f, 0.f};
#pragma unroll
  for (int qs = 0; qs < 2; ++qs)
#pragma unroll
    for (int es = 0; es < 4; ++es) nacc[qs][es] = (f32x4){0.f, 0.f, 0.f, 0.f};

  bf16_t* wbuf = &Wb[wv][0];

  for (int st = 0; st < 16; ++st) {
    int s0 = st * 128;
    __syncthreads();  // previous tile's compute done
    // stage K [128 s][64 d]
#pragma unroll
    for (int s4 = 0; s4 < 4; ++s4) {
      int t = s4 * 256 + tid;
      int row = t >> 3, u = t & 7;
      int cc = (u ^ (row & 7)) << 3;
      GLDS16(Pk + (size_t)(s0 + row) * 4096 + cc, &Ks[t * 8]);
    }
    // stage V^T [64 e][128 s]
#pragma unroll
    for (int s4 = 0; s4 < 4; ++s4) {
      int t = s4 * 256 + tid;
      int row = t >> 4, u = t & 15;
      int cc = (u ^ (row & 7)) << 3;
      GLDS16(Vg + (size_t)row * 4096 + s0 + cc, &Vts[t * 8]);
    }
    __syncthreads();  // barrier drains vmcnt: Ks/Vts ready

    // QK^T (swapped): S[s][q]; d2 = k2 + q2 - 2 q.k; w = 1/d2
#pragma unroll
    for (int ss = 0; ss < 8; ++ss) {
      int srow = ss * 16 + l15;
      bf16x8 kf0 = *(const bf16x8*)&Ks[srow * 64 + ((lhi ^ (srow & 7)) << 3)];
      bf16x8 kf1 = *(const bf16x8*)&Ks[srow * 64 + (((4 + lhi) ^ (srow & 7)) << 3)];
      f32x4 k2v = *(const f32x4*)(K2g + s0 + ss * 16 + lhi * 4);
#pragma unroll
      for (int qs = 0; qs < 2; ++qs) {
        f32x4 S = mfma_bf16(kf0, qm[qs][0], k2v);
        S = mfma_bf16(kf1, qm[qs][1], S);
        bf16x4 wv4;
#pragma unroll
        for (int r = 0; r < 4; ++r) {
          float d2 = S[r] + q2v[qs];
          float w = __builtin_amdgcn_rcpf(fmaxf(d2, 1e-12f));
          dacc[qs] += w;
          wv4[r] = (__bf16)w;
        }
        *(bf16x4*)&wbuf[(qs * 16 + l15) * 136 + ss * 16 + lhi * 4] = wv4;
      }
    }
    // PV: numer[q][e] += w[q][s] * Vt[e][s]
#pragma unroll
    for (int sk = 0; sk < 4; ++sk) {
      bf16x8 wf[2], vf[4];
#pragma unroll
      for (int qs = 0; qs < 2; ++qs)
        wf[qs] = *(const bf16x8*)&wbuf[(qs * 16 + l15) * 136 + sk * 32 + lhi * 8];
#pragma unroll
      for (int es = 0; es < 4; ++es) {
        int row = es * 16 + l15;
        vf[es] = *(const bf16x8*)&Vts[row * 128 + (((sk * 4 + lhi) ^ (row & 7)) << 3)];
      }
#pragma unroll
      for (int qs = 0; qs < 2; ++qs)
#pragma unroll
        for (int es = 0; es < 4; ++es)
          nacc[qs][es] = mfma_bf16(wf[qs], vf[es], nacc[qs][es]);
    }
  }

  // denom: reduce over lhi groups (lanes sharing l15)
#pragma unroll
  for (int qs = 0; qs < 2; ++qs) {
    dacc[qs] += __shfl_xor(dacc[qs], 16);
    dacc[qs] += __shfl_xor(dacc[qs], 32);
  }

  // epilogue: A = numer/(eps+denom); H = G*A
#pragma unroll
  for (int qs = 0; qs < 2; ++qs)
#pragma unroll
    for (int r = 0; r < 4; ++r) {
      int tq = q0 + qs * 16 + lhi * 4 + r;
      float dn = __shfl(dacc[qs], lhi * 4 + r);
      float inv = __builtin_amdgcn_rcpf(ATT_EPS + dn);
#pragma unroll
      for (int es = 0; es < 4; ++es) {
        int ec = es * 16 + l15;
        float g = (float)Pg[(size_t)tq * 4096 + ec];
        float hv = g * nacc[qs][es][r] * inv;
        H[(size_t)(rowbase + tq) * 1024 + h * 64 + ec] = (bf16_t)hv;
      }
    }
}

// ------------------------------------------------------------------ launcher
extern "C" void kernel_launch(void* const* d_in, const int* in_sizes, int n_in,
                              void* d_out, int out_size, void* d_ws, size_t ws_size,
                              hipStream_t stream) {
  const float* X     = (const float*)d_in[0];
  const float* W_in  = (const float*)d_in[1];
  const float* b_in  = (const float*)d_in[2];
  const float* W_out = (const float*)d_in[3];
  const float* b_out = (const float*)d_in[4];

  char* ws = (char*)d_ws;
  bf16_t* Xb  = (bf16_t*)(ws);                        // 8 MB (dead after gemm1)
  bf16_t* VtG = (bf16_t*)(ws);                        // 8 MB (reuses Xb region)
  bf16_t* WbT = (bf16_t*)(ws + ((size_t)8  << 20));   // 8 MB
  bf16_t* WoT = (bf16_t*)(ws + ((size_t)16 << 20));   // 2 MB
  bf16_t* Pb  = (bf16_t*)(ws + ((size_t)18 << 20));   // 32 MB
  bf16_t* Hb  = (bf16_t*)(ws + ((size_t)50 << 20));   // 8 MB
  float*  Q2  = (float*) (ws + ((size_t)58 << 20));   // 256 KB
  float*  K2  = (float*) (ws + ((size_t)59 << 20));   // 256 KB

  cvt_x_kernel<<<2048, 256, 0, stream>>>(X, Xb, 4096 * 1024 / 8);
  tcvt_kernel<<<dim3(64, 16), 256, 0, stream>>>(W_in, WbT, 1024, 4096);
  tcvt_kernel<<<dim3(16, 16), 256, 0, stream>>>(W_out, WoT, 1024, 1024);
  gemm_kernel<0><<<1024, 256, 0, stream>>>(Xb, WbT, b_in, Pb, 4096, 4096, 1024);
  norms_kernel<<<2048, 256, 0, stream>>>(Pb, Q2, K2);
  vt_kernel<<<dim3(16, 64), 256, 0, stream>>>(Pb, VtG);
  attn_kernel<<<512, 256, 0, stream>>>(Pb, VtG, Q2, K2, Hb);
  gemm_kernel<1><<<256, 256, 0, stream>>>(Hb, WoT, b_out, d_out, 4096, 1024, 1024);
}